// Round 1
// baseline (345.249 us; speedup 1.0000x reference)
//
#include <hip/hip_runtime.h>

// Problem constants
constexpr int B  = 64;
constexpr int U  = 512;
constexpr int AE = 1024;
constexpr int UE = 256;
constexpr int A  = 256;     // head size
constexpr int KQ = AE + UE; // 1280

typedef _Float16 f16x8 __attribute__((ext_vector_type(8)));
typedef float    f32x4 __attribute__((ext_vector_type(4)));

// async global(fp16 data)->LDS, 16B per lane; lds dest must be wave-uniform-base + lane*16
__device__ __forceinline__ void cp16(void* lds, const void* g) {
    __builtin_amdgcn_global_load_lds(
        (const __attribute__((address_space(1))) void*)g,
        (__attribute__((address_space(3))) void*)lds, 16, 0, 0);
}

// ---------------------------------------------------------------------------
// K0: cast+transpose weights to fp16 [N][K] so GEMM B-frags are k-contiguous
// ---------------------------------------------------------------------------
__global__ void prep(const float* __restrict__ Wq, const float* __restrict__ Wk,
                     _Float16* __restrict__ WqT, _Float16* __restrict__ WkT) {
    int idx = blockIdx.x * 256 + threadIdx.x;
    if (idx < KQ * A) {
        int k = idx >> 8, n = idx & 255;
        WqT[(size_t)n * KQ + k] = (_Float16)Wq[idx];
    } else {
        int j = idx - KQ * A;
        if (j < A * A) {
            int k = j >> 8, n = j & 255;
            WkT[(size_t)n * A + k] = (_Float16)Wk[j];
        }
    }
}

// ---------------------------------------------------------------------------
// K1/K2: C[m][n] = (concat A1|A2)[m][k] * BT[n][k] + bias[n], output fp16.
// BM=64, BN=256 (full N -> A read exactly once), BK=64 (2 planes of 32),
// 8 waves (512 thr), wave tile 32x64 = 2x4 tiles of 16x16, mfma 16x16x32 f16.
// ---------------------------------------------------------------------------
__global__ __launch_bounds__(512) void gemm(
    const float* __restrict__ A1, int s1, int split,
    const float* __restrict__ A2, int s2,
    const _Float16* __restrict__ BT,   // [256][Ktot] fp16
    const float* __restrict__ bias,    // [256]
    _Float16* __restrict__ Out,        // [M][256] fp16
    int Ktot)
{
    __shared__ __align__(16) _Float16 Al[2][64][32];   // 8 KB
    __shared__ __align__(16) _Float16 Bl[2][256][32];  // 32 KB

    const int t    = threadIdx.x;
    const int lane = t & 63;
    const int w    = t >> 6;              // 0..7
    const int mbase = blockIdx.x * 64;

    const int wm = (w & 1) * 32;          // wave row base
    const int wn = (w >> 1) * 64;         // wave col base

    f32x4 acc[2][4] = {};

    // A staging mapping: thread -> (row, 8-elem chunk)
    const int ar  = t >> 3;               // 0..63
    const int aq  = t & 7;                // 0..7  (k-chunk of 8)
    const int ap  = aq >> 2;              // plane
    const int aq8 = (aq & 3) * 8;
    const size_t grow = mbase + ar;

    const int nk = Ktot >> 6;
    for (int kb = 0; kb < nk; kb++) {
        const int k0 = kb * 64;
        __syncthreads();   // protect LDS from previous iter's readers
        // B: async fp16 global->LDS, 32KB = 4 rounds x 512 thr x 16B
        #pragma unroll
        for (int rnd = 0; rnd < 4; rnd++) {
            int s = rnd * 512 + t;
            int p = s >> 10;
            int n = (s & 1023) >> 2;
            int q = s & 3;
            cp16((char*)&Bl[0][0][0] + (size_t)s * 16,
                 BT + (size_t)n * Ktot + (k0 + p * 32 + q * 8));
        }
        // A: fp32 load -> cvt f16 -> ds_write_b128
        {
            int kg = k0 + aq * 8;
            const float* src = (kg < split) ? (A1 + grow * (size_t)s1 + kg)
                                            : (A2 + grow * (size_t)s2 + (kg - split));
            const float4 x = *(const float4*)src;
            const float4 y = *(const float4*)(src + 4);
            f16x8 hv;
            hv[0] = (_Float16)x.x; hv[1] = (_Float16)x.y;
            hv[2] = (_Float16)x.z; hv[3] = (_Float16)x.w;
            hv[4] = (_Float16)y.x; hv[5] = (_Float16)y.y;
            hv[6] = (_Float16)y.z; hv[7] = (_Float16)y.w;
            *(f16x8*)(&Al[ap][ar][aq8]) = hv;
        }
        __syncthreads();   // drains vmcnt (async B) + lgkm (A writes)
        #pragma unroll
        for (int p = 0; p < 2; p++) {
            f16x8 af[2], bf[4];
            #pragma unroll
            for (int mt = 0; mt < 2; mt++)
                af[mt] = *(const f16x8*)(&Al[p][wm + mt * 16 + (lane & 15)][(lane >> 4) * 8]);
            #pragma unroll
            for (int nt = 0; nt < 4; nt++)
                bf[nt] = *(const f16x8*)(&Bl[p][wn + nt * 16 + (lane & 15)][(lane >> 4) * 8]);
            #pragma unroll
            for (int mt = 0; mt < 2; mt++)
                #pragma unroll
                for (int nt = 0; nt < 4; nt++)
                    acc[mt][nt] = __builtin_amdgcn_mfma_f32_16x16x32_f16(
                        af[mt], bf[nt], acc[mt][nt], 0, 0, 0);
        }
    }
    // epilogue: C layout col=lane&15, row=(lane>>4)*4+reg
    const int col0 = wn + (lane & 15);
    const int rsub = (lane >> 4) * 4;
    #pragma unroll
    for (int nt = 0; nt < 4; nt++) {
        const int col = col0 + nt * 16;
        const float bv = bias[col];
        #pragma unroll
        for (int mt = 0; mt < 2; mt++)
            #pragma unroll
            for (int r = 0; r < 4; r++) {
                int row = mbase + wm + mt * 16 + rsub + r;
                Out[(size_t)row * 256 + col] = (_Float16)(acc[mt][nt][r] + bv);
            }
    }
}

// ---------------------------------------------------------------------------
// K3: per (batch, 32-row q-tile): S = Qh Kh^T / 16, multiplicative mask,
// row softmax, fp32 out. 4 waves, wave owns 128 cols (8 n-tiles x 2 m-tiles).
// ---------------------------------------------------------------------------
__global__ __launch_bounds__(256) void attn(
    const _Float16* __restrict__ Qh, const _Float16* __restrict__ Kh,
    const int* __restrict__ nr_own_units, const int* __restrict__ nr_units_enemy,
    const int* __restrict__ nr_own_flags, float* __restrict__ Out)
{
    __shared__ __align__(16) char smem[81920];
    _Float16 (*Kl)[512][32] = (_Float16(*)[512][32])smem;            // 2 planes, 64 KB
    _Float16 (*Ql)[32][32]  = (_Float16(*)[32][32])(smem + 65536);   // 8 planes, 16 KB
    float (*S)[516] = (float(*)[516])smem;                           // overlays K staging (dead by then)

    const int t    = threadIdx.x;
    const int lane = t & 63;
    const int w    = t >> 6;                 // 0..3
    const int b    = blockIdx.y;
    const int qbase = blockIdx.x * 32;

    const int nf = nr_own_flags[b];
    const int nu = nr_own_units[b];
    const int ne = nr_units_enemy[b];

    // Q tile: 16 KB async, 4 rounds
    const _Float16* Qb = Qh + ((size_t)b * 512 + qbase) * 256;
    #pragma unroll
    for (int rnd = 0; rnd < 4; rnd++) {
        int s = rnd * 256 + t;
        int p = s >> 7;
        int row = (s & 127) >> 2;
        int q = s & 3;
        cp16((char*)(smem + 65536) + (size_t)s * 16,
             Qb + (size_t)row * 256 + p * 32 + q * 8);
    }

    f32x4 acc[2][8] = {};
    const _Float16* Kb = Kh + (size_t)b * 512 * 256;
    const int wn = w * 128;

    for (int c = 0; c < 4; c++) {          // 64-d chunks
        __syncthreads();
        #pragma unroll
        for (int rnd = 0; rnd < 16; rnd++) {
            int s = rnd * 256 + t;         // 0..4095
            int p = s >> 11;
            int row = (s & 2047) >> 2;
            int q = s & 3;
            cp16(smem + (size_t)s * 16,
                 Kb + (size_t)row * 256 + c * 64 + p * 32 + q * 8);
        }
        __syncthreads();                   // drains async loads (Q ready on c==0 too)
        #pragma unroll
        for (int p = 0; p < 2; p++) {
            f16x8 af[2], bf[8];
            #pragma unroll
            for (int mt = 0; mt < 2; mt++)
                af[mt] = *(const f16x8*)(&Ql[c * 2 + p][mt * 16 + (lane & 15)][(lane >> 4) * 8]);
            #pragma unroll
            for (int nt = 0; nt < 8; nt++)
                bf[nt] = *(const f16x8*)(&Kl[p][wn + nt * 16 + (lane & 15)][(lane >> 4) * 8]);
            #pragma unroll
            for (int mt = 0; mt < 2; mt++)
                #pragma unroll
                for (int nt = 0; nt < 8; nt++)
                    acc[mt][nt] = __builtin_amdgcn_mfma_f32_16x16x32_f16(
                        af[mt], bf[nt], acc[mt][nt], 0, 0, 0);
        }
    }

    __syncthreads();   // all mfma reads of Kl/Ql done; safe to overlay S
    const int rsub = (lane >> 4) * 4;
    #pragma unroll
    for (int nt = 0; nt < 8; nt++) {
        const int col = wn + nt * 16 + (lane & 15);
        const bool cok = col < ne;
        #pragma unroll
        for (int mt = 0; mt < 2; mt++)
            #pragma unroll
            for (int r = 0; r < 4; r++) {
                int row = mt * 16 + rsub + r;
                int uq = qbase + row;
                bool ok = cok && (uq >= nf) && (uq < nu);
                S[row][col] = acc[mt][nt][r] * 0.0625f * (ok ? 1.0f : 1e-9f);
            }
    }
    __syncthreads();

    // softmax: wave w -> rows [w*8, w*8+8)
    for (int rr = 0; rr < 8; rr++) {
        const int row = w * 8 + rr;
        float v[8], m = -1e30f;
        #pragma unroll
        for (int i = 0; i < 8; i++) { v[i] = S[row][lane + i * 64]; m = fmaxf(m, v[i]); }
        #pragma unroll
        for (int off = 32; off >= 1; off >>= 1) m = fmaxf(m, __shfl_xor(m, off));
        float e[8], sum = 0.f;
        #pragma unroll
        for (int i = 0; i < 8; i++) { e[i] = __expf(v[i] - m); sum += e[i]; }
        #pragma unroll
        for (int off = 32; off >= 1; off >>= 1) sum += __shfl_xor(sum, off);
        const float inv = 1.0f / sum;
        float* orow = Out + ((size_t)b * 512 + qbase + row) * 512;
        #pragma unroll
        for (int i = 0; i < 8; i++) orow[lane + i * 64] = e[i] * inv;
    }
}

// ---------------------------------------------------------------------------
extern "C" void kernel_launch(void* const* d_in, const int* in_sizes, int n_in,
                              void* d_out, int out_size, void* d_ws, size_t ws_size,
                              hipStream_t stream) {
    const float* ar    = (const float*)d_in[0];   // [B,U,AE]
    const float* own   = (const float*)d_in[1];   // [B,U,UE]
    const float* enemy = (const float*)d_in[2];   // [B,U,UE]
    const int*   n_own   = (const int*)d_in[3];   // nr_own_units
    const int*   n_enemy = (const int*)d_in[4];   // nr_units_enemy
    const int*   n_flags = (const int*)d_in[5];   // nr_own_flags
    const float* Wq = (const float*)d_in[6];
    const float* bq = (const float*)d_in[7];
    const float* Wk = (const float*)d_in[8];
    const float* bk = (const float*)d_in[9];
    float* out = (float*)d_out;

    char* ws = (char*)d_ws;
    _Float16* WqT = (_Float16*)(ws);                       // 256x1280 = 655360 B
    _Float16* WkT = (_Float16*)(ws + 655360);              // 256x256  = 131072 B
    _Float16* Qh  = (_Float16*)(ws + 786432);              // 32768x256 = 16777216 B
    _Float16* Kh  = (_Float16*)(ws + 786432 + 16777216);   // 32768x256

    prep<<<dim3((KQ * A + A * A) / 256), dim3(256), 0, stream>>>(Wq, Wk, WqT, WkT);

    // Q = concat(ar, own) @ Wq + bq
    gemm<<<dim3(512), dim3(512), 0, stream>>>(ar, AE, AE, own, UE, WqT, bq, Qh, KQ);
    // K = enemy @ Wk + bk
    gemm<<<dim3(512), dim3(512), 0, stream>>>(nullptr, 0, 0, enemy, UE, WkT, bk, Kh, A);

    attn<<<dim3(16, B), dim3(256), 0, stream>>>(Qh, Kh, n_own, n_enemy, n_flags, out);
}

// Round 2
// 331.446 us; speedup vs baseline: 1.0416x; 1.0416x over previous
//
#include <hip/hip_runtime.h>

// Problem constants
constexpr int B  = 64;
constexpr int U  = 512;
constexpr int AE = 1024;
constexpr int UE = 256;
constexpr int A  = 256;     // head size
constexpr int KQ = AE + UE; // 1280

typedef _Float16 f16x8 __attribute__((ext_vector_type(8)));
typedef float    f32x4 __attribute__((ext_vector_type(4)));

// ---------------------------------------------------------------------------
// K0: cast+transpose weights to fp16 [N][K] so GEMM B-frags are k-contiguous
// ---------------------------------------------------------------------------
__global__ void prep(const float* __restrict__ Wq, const float* __restrict__ Wk,
                     _Float16* __restrict__ WqT, _Float16* __restrict__ WkT) {
    int idx = blockIdx.x * 256 + threadIdx.x;
    if (idx < KQ * A) {
        int k = idx >> 8, n = idx & 255;
        WqT[(size_t)n * KQ + k] = (_Float16)Wq[idx];
    } else {
        int j = idx - KQ * A;
        if (j < A * A) {
            int k = j >> 8, n = j & 255;
            WkT[(size_t)n * A + k] = (_Float16)Wk[j];
        }
    }
}

// ---------------------------------------------------------------------------
// K1/K2: C[m][n] = (concat A1|A2)[m][k] * BT[n][k] + bias[n], fp16 out in
// permuted layout [b=row>>9][c=col>>5][u=row&511][col&31] for attn streaming.
// BM=64, BN=256, BK=64, 512 thr / 8 waves, wave tile 32x64 (2x4 of 16x16).
// Register-prefetch pipeline: global->VGPR for iter k+1 overlaps MFMA of k.
// LDS tiles bank-swizzled: 16B-chunk index ^= (row>>1)&3 (2-way max = free).
// ---------------------------------------------------------------------------
__global__ __launch_bounds__(512) void gemm(
    const float* __restrict__ A1, int s1, int split,
    const float* __restrict__ A2, int s2,
    const _Float16* __restrict__ BT,   // [256][Ktot] fp16
    const float* __restrict__ bias,    // [256]
    _Float16* __restrict__ Out,        // permuted, see above
    int Ktot)
{
    __shared__ __align__(16) _Float16 Al[2][64][32];   // 8 KB  (2 k-planes of 32)
    __shared__ __align__(16) _Float16 Bl[2][256][32];  // 32 KB

    const int t    = threadIdx.x;
    const int lane = t & 63;
    const int w    = t >> 6;              // 0..7
    const int mbase = blockIdx.x * 64;

    const int wm = (w & 1) * 32;          // wave row base
    const int wn = (w >> 1) * 64;         // wave col base

    f32x4 acc[2][4] = {};

    // A staging mapping: thread -> (row ar, 8-elem k-chunk aq)
    const int ar  = t >> 3;               // 0..63
    const int aq  = t & 7;                // 0..7
    const int ap  = aq >> 2;              // plane
    const int asw = ((aq & 3) ^ ((ar >> 1) & 3)) * 8;  // swizzled chunk offset
    const size_t grow = mbase + ar;

    // B staging mapping: s = j*512 + t
    int bp[4], bn[4], bq[4], bsw[4];
    #pragma unroll
    for (int j = 0; j < 4; j++) {
        int s = j * 512 + t;
        bp[j] = s >> 10;
        bn[j] = (s & 1023) >> 2;
        bq[j] = s & 3;
        bsw[j] = ((bq[j] ^ ((bn[j] >> 1) & 3))) * 8;
    }

    float4 areg0, areg1;
    f16x8 breg[4];

    auto loadA = [&](int k0) {
        int kg = k0 + aq * 8;
        const float* src = (kg < split) ? (A1 + grow * (size_t)s1 + kg)
                                        : (A2 + grow * (size_t)s2 + (kg - split));
        areg0 = ((const float4*)src)[0];
        areg1 = ((const float4*)src)[1];
    };
    auto loadB = [&](int k0) {
        #pragma unroll
        for (int j = 0; j < 4; j++)
            breg[j] = *(const f16x8*)(BT + (size_t)bn[j] * Ktot + k0 + bp[j] * 32 + bq[j] * 8);
    };

    loadA(0);
    loadB(0);

    const int rsw = (((lane & 15) >> 1) & 3);  // read-side swizzle component
    const int nk = Ktot >> 6;
    for (int kb = 0; kb < nk; kb++) {
        __syncthreads();   // prev iter's LDS readers done
        {   // ds_write staged regs (compiler inserts vmcnt wait here)
            f16x8 hv;
            hv[0] = (_Float16)areg0.x; hv[1] = (_Float16)areg0.y;
            hv[2] = (_Float16)areg0.z; hv[3] = (_Float16)areg0.w;
            hv[4] = (_Float16)areg1.x; hv[5] = (_Float16)areg1.y;
            hv[6] = (_Float16)areg1.z; hv[7] = (_Float16)areg1.w;
            *(f16x8*)(&Al[ap][ar][asw]) = hv;
            #pragma unroll
            for (int j = 0; j < 4; j++)
                *(f16x8*)(&Bl[bp[j]][bn[j]][bsw[j]]) = breg[j];
        }
        __syncthreads();
        if (kb + 1 < nk) { loadA(kb * 64 + 64); loadB(kb * 64 + 64); }
        #pragma unroll
        for (int p = 0; p < 2; p++) {
            f16x8 af[2], bf[4];
            #pragma unroll
            for (int mt = 0; mt < 2; mt++)
                af[mt] = *(const f16x8*)(&Al[p][wm + mt * 16 + (lane & 15)][(((lane >> 4) ^ rsw)) * 8]);
            #pragma unroll
            for (int nt = 0; nt < 4; nt++)
                bf[nt] = *(const f16x8*)(&Bl[p][wn + nt * 16 + (lane & 15)][(((lane >> 4) ^ rsw)) * 8]);
            #pragma unroll
            for (int mt = 0; mt < 2; mt++)
                #pragma unroll
                for (int nt = 0; nt < 4; nt++)
                    acc[mt][nt] = __builtin_amdgcn_mfma_f32_16x16x32_f16(
                        af[mt], bf[nt], acc[mt][nt], 0, 0, 0);
        }
    }
    // epilogue: C layout col=lane&15, row=(lane>>4)*4+reg; permuted store
    const int col0 = wn + (lane & 15);
    const int rsub = (lane >> 4) * 4;
    #pragma unroll
    for (int nt = 0; nt < 4; nt++) {
        const int col = col0 + nt * 16;
        const float bv = bias[col];
        const int c5 = col >> 5, c31 = col & 31;
        #pragma unroll
        for (int mt = 0; mt < 2; mt++)
            #pragma unroll
            for (int r = 0; r < 4; r++) {
                int row = mbase + wm + mt * 16 + rsub + r;
                int bb = row >> 9, u = row & 511;
                Out[(((size_t)bb * 8 + c5) * 512 + u) * 32 + c31] =
                    (_Float16)(acc[mt][nt][r] + bv);
            }
    }
}

// ---------------------------------------------------------------------------
// K3: block = (batch, 64 q-rows), 512 thr / 8 waves. S = Qh Kh^T / 16 with
// multiplicative mask, row softmax entirely in registers + tiny LDS combine.
// K streamed in 8 chunks of 32 d via register-prefetch pipeline.
// ---------------------------------------------------------------------------
__global__ __launch_bounds__(512) void attn(
    const _Float16* __restrict__ Qh, const _Float16* __restrict__ Kh,
    const int* __restrict__ nr_own_units, const int* __restrict__ nr_units_enemy,
    const int* __restrict__ nr_own_flags, float* __restrict__ Out)
{
    __shared__ __align__(16) _Float16 Ql[8][64][32];   // 32 KB, 8 d-chunks
    __shared__ __align__(16) _Float16 Kl[512][32];     // 32 KB, one d-chunk
    __shared__ float red[64][4];                       // per-row cross-wave scratch

    const int t    = threadIdx.x;
    const int lane = t & 63;
    const int w    = t >> 6;                 // 0..7
    const int b    = blockIdx.y;
    const int qbase = blockIdx.x * 64;

    const int nf = nr_own_flags[b];
    const int nu = nr_own_units[b];
    const int ne = nr_units_enemy[b];

    const int wm = (w & 1) * 32;             // wave row base (0/32)
    const int wn = (w >> 1) * 128;           // wave col base (0..384)

    // ---- stage Q (once): regs -> LDS, swizzled
    f16x8 qreg[4];
    {
        const _Float16* Qb = Qh + ((size_t)b * 8 * 512 + qbase) * 32;
        #pragma unroll
        for (int j = 0; j < 4; j++) {
            int s = j * 512 + t;
            int p = s >> 8, row = (s & 255) >> 2, cq = s & 3;
            qreg[j] = *(const f16x8*)(Qb + ((size_t)p * 512 + row) * 32 + cq * 8);
        }
        #pragma unroll
        for (int j = 0; j < 4; j++) {
            int s = j * 512 + t;
            int p = s >> 8, row = (s & 255) >> 2, cq = s & 3;
            *(f16x8*)(&Ql[p][row][(cq ^ ((row >> 1) & 3)) * 8]) = qreg[j];
        }
    }

    // ---- K chunk staging mapping: s = j*512 + t -> row = s>>2, cq = s&3
    const _Float16* Kb = Kh + (size_t)b * 8 * 512 * 32;
    f16x8 kreg[4];
    const int krow = t >> 2;                 // + j*128
    const int kq   = t & 3;
    auto loadK = [&](int c) {
        const _Float16* Kc = Kb + (size_t)c * 512 * 32;
        #pragma unroll
        for (int j = 0; j < 4; j++)
            kreg[j] = *(const f16x8*)(Kc + ((size_t)(j * 128 + krow)) * 32 + kq * 8);
    };
    loadK(0);

    f32x4 acc[2][8] = {};
    const int rsw = (((lane & 15) >> 1) & 3);
    for (int c = 0; c < 8; c++) {
        __syncthreads();   // c==0: publish Ql; else: prev Kl readers done
        #pragma unroll
        for (int j = 0; j < 4; j++) {
            int row = j * 128 + krow;
            *(f16x8*)(&Kl[row][(kq ^ ((row >> 1) & 3)) * 8]) = kreg[j];
        }
        __syncthreads();
        if (c < 7) loadK(c + 1);
        f16x8 af[2], bf[8];
        #pragma unroll
        for (int mt = 0; mt < 2; mt++)
            af[mt] = *(const f16x8*)(&Ql[c][wm + mt * 16 + (lane & 15)][((lane >> 4) ^ rsw) * 8]);
        #pragma unroll
        for (int nt = 0; nt < 8; nt++)
            bf[nt] = *(const f16x8*)(&Kl[wn + nt * 16 + (lane & 15)][((lane >> 4) ^ rsw) * 8]);
        #pragma unroll
        for (int mt = 0; mt < 2; mt++)
            #pragma unroll
            for (int nt = 0; nt < 8; nt++)
                acc[mt][nt] = __builtin_amdgcn_mfma_f32_16x16x32_f16(
                    af[mt], bf[nt], acc[mt][nt], 0, 0, 0);
    }

    // ---- mask + scale in registers
    const int rsub = (lane >> 4) * 4;
    #pragma unroll
    for (int mt = 0; mt < 2; mt++)
        #pragma unroll
        for (int nt = 0; nt < 8; nt++)
            #pragma unroll
            for (int r = 0; r < 4; r++) {
                int rl = wm + mt * 16 + rsub + r;
                int uq = qbase + rl;
                int col = wn + nt * 16 + (lane & 15);
                bool ok = (col < ne) && (uq >= nf) && (uq < nu);
                acc[mt][nt][r] = acc[mt][nt][r] * 0.0625f * (ok ? 1.0f : 1e-9f);
            }

    // ---- row max: over nt in-lane, then across 16-lane group, then cross-wave
    float mx[2][4];
    #pragma unroll
    for (int mt = 0; mt < 2; mt++)
        #pragma unroll
        for (int r = 0; r < 4; r++) {
            float m = acc[mt][0][r];
            #pragma unroll
            for (int nt = 1; nt < 8; nt++) m = fmaxf(m, acc[mt][nt][r]);
            #pragma unroll
            for (int off = 1; off <= 8; off <<= 1) m = fmaxf(m, __shfl_xor(m, off));
            mx[mt][r] = m;
        }
    if ((lane & 15) == 0) {
        #pragma unroll
        for (int mt = 0; mt < 2; mt++)
            #pragma unroll
            for (int r = 0; r < 4; r++)
                red[wm + mt * 16 + rsub + r][w >> 1] = mx[mt][r];
    }
    __syncthreads();
    #pragma unroll
    for (int mt = 0; mt < 2; mt++)
        #pragma unroll
        for (int r = 0; r < 4; r++) {
            f32x4 v = *(const f32x4*)(&red[wm + mt * 16 + rsub + r][0]);
            mx[mt][r] = fmaxf(fmaxf(v[0], v[1]), fmaxf(v[2], v[3]));
        }
    __syncthreads();   // everyone read max before red is reused for sums

    // ---- exp + row sum
    float sm[2][4];
    #pragma unroll
    for (int mt = 0; mt < 2; mt++)
        #pragma unroll
        for (int r = 0; r < 4; r++) {
            float s = 0.f;
            #pragma unroll
            for (int nt = 0; nt < 8; nt++) {
                float e = __expf(acc[mt][nt][r] - mx[mt][r]);
                acc[mt][nt][r] = e;
                s += e;
            }
            #pragma unroll
            for (int off = 1; off <= 8; off <<= 1) s += __shfl_xor(s, off);
            sm[mt][r] = s;
        }
    if ((lane & 15) == 0) {
        #pragma unroll
        for (int mt = 0; mt < 2; mt++)
            #pragma unroll
            for (int r = 0; r < 4; r++)
                red[wm + mt * 16 + rsub + r][w >> 1] = sm[mt][r];
    }
    __syncthreads();

    // ---- normalize + store
    #pragma unroll
    for (int mt = 0; mt < 2; mt++)
        #pragma unroll
        for (int r = 0; r < 4; r++) {
            int rl = wm + mt * 16 + rsub + r;
            f32x4 v = *(const f32x4*)(&red[rl][0]);
            float inv = 1.0f / (v[0] + v[1] + v[2] + v[3]);
            float* orow = Out + ((size_t)b * 512 + qbase + rl) * 512 + wn + (lane & 15);
            #pragma unroll
            for (int nt = 0; nt < 8; nt++)
                orow[nt * 16] = acc[mt][nt][r] * inv;
        }
}

// ---------------------------------------------------------------------------
extern "C" void kernel_launch(void* const* d_in, const int* in_sizes, int n_in,
                              void* d_out, int out_size, void* d_ws, size_t ws_size,
                              hipStream_t stream) {
    const float* ar    = (const float*)d_in[0];   // [B,U,AE]
    const float* own   = (const float*)d_in[1];   // [B,U,UE]
    const float* enemy = (const float*)d_in[2];   // [B,U,UE]
    const int*   n_own   = (const int*)d_in[3];   // nr_own_units
    const int*   n_enemy = (const int*)d_in[4];   // nr_units_enemy
    const int*   n_flags = (const int*)d_in[5];   // nr_own_flags
    const float* Wq = (const float*)d_in[6];
    const float* bq = (const float*)d_in[7];
    const float* Wk = (const float*)d_in[8];
    const float* bk = (const float*)d_in[9];
    float* out = (float*)d_out;

    char* ws = (char*)d_ws;
    _Float16* WqT = (_Float16*)(ws);                       // 256x1280 = 655360 B
    _Float16* WkT = (_Float16*)(ws + 655360);              // 256x256  = 131072 B
    _Float16* Qh  = (_Float16*)(ws + 786432);              // [64][8][512][32] f16
    _Float16* Kh  = (_Float16*)(ws + 786432 + 16777216);   // [64][8][512][32] f16

    prep<<<dim3((KQ * A + A * A) / 256), dim3(256), 0, stream>>>(Wq, Wk, WqT, WkT);

    // Q = concat(ar, own) @ Wq + bq
    gemm<<<dim3(512), dim3(512), 0, stream>>>(ar, AE, AE, own, UE, WqT, bq, Qh, KQ);
    // K = enemy @ Wk + bk  (split=0 -> always A2 path)
    gemm<<<dim3(512), dim3(512), 0, stream>>>(enemy, UE, 0, enemy, UE, WkT, bk, Kh, A);

    attn<<<dim3(8, B), dim3(512), 0, stream>>>(Qh, Kh, n_own, n_enemy, n_flags, out);
}